// Round 4
// baseline (397.012 us; speedup 1.0000x reference)
//
#include <hip/hip_runtime.h>
#include <math.h>

#define N_ROWS 200000
#define D 200
#define OUT1 300
#define OUT2 400

#define S1B 1000                    // stage-1 blocks per branch
#define Q_TOTAL 10000000            // float4s per branch (200000*200/4)
#define Q_STRIDE (S1B * 256)        // 256,000 float4s per grid pass
                                    // float stride 1,024,000 % 200 == 0 ->
                                    // each thread's float4 = fixed column quad

// ---------------------------------------------------------------------------
// Stage 1: column-sum of [N_ROWS, D] f32 (branch = blockIdx.y).
// Copy-style flat walk: lane-contiguous, 128B-aligned 1KB wave-loads; the
// whole grid covers a dense window each iteration (m13 pattern).
// Thread t of block b always reads column-quad q = (6b + t) % 50.
// partial layout: [2][S1B][D] floats (float4-coalesced 800B store/block).
// ---------------------------------------------------------------------------
__global__ __launch_bounds__(256)
void colsum_kernel(const float* __restrict__ userH,
                   const float* __restrict__ postH,
                   float* __restrict__ partial)
{
    const int br  = blockIdx.y;
    const int bid = blockIdx.x;
    const int t   = threadIdx.x;
    const float4* __restrict__ H4 =
        reinterpret_cast<const float4*>(br ? postH : userH);

    float4 acc = make_float4(0.f, 0.f, 0.f, 0.f);
    int idx = bid * 256 + t;
    // 39 full passes (39 * 256000 = 9,984,000 < 10,000,000), then guarded tail.
    for (int k = 0; k < 39; ++k) {
        const float4 v = H4[idx];
        acc.x += v.x; acc.y += v.y; acc.z += v.z; acc.w += v.w;
        idx += Q_STRIDE;
    }
    if (idx < Q_TOTAL) {
        const float4 v = H4[idx];
        acc.x += v.x; acc.y += v.y; acc.z += v.z; acc.w += v.w;
    }

    // Combine 256 thread-accumulators into 50 column-quads via rotation table.
    __shared__ float4 part[6][50];   // 4.8 KB
    const int q = (6 * bid + t) % 50;   // this thread's column quad
    if (t < 50) part[5][t] = make_float4(0.f, 0.f, 0.f, 0.f); // group 5 sparse
    __syncthreads();
    part[t / 50][q] = acc;           // distinct slots within each group
    __syncthreads();

    if (t < 50) {
        float4 s = make_float4(0.f, 0.f, 0.f, 0.f);
        #pragma unroll
        for (int g = 0; g < 6; ++g) {
            const float4 v = part[g][t];
            s.x += v.x; s.y += v.y; s.z += v.z; s.w += v.w;
        }
        reinterpret_cast<float4*>(
            partial + ((size_t)br * S1B + bid) * D)[t] = s;
    }
}

// ---------------------------------------------------------------------------
// Stage 2: finish reduction -> means -> MLP -> softmax -> sigmoid scalar.
// One block, 1024 threads; chunked dots, float4 along output dims.
// ---------------------------------------------------------------------------
__global__ __launch_bounds__(1024)
void mlp_kernel(const float* __restrict__ partial,
                const float* __restrict__ W1u, const float* __restrict__ b1u,
                const float* __restrict__ W2u, const float* __restrict__ b2u,
                const float* __restrict__ W1p, const float* __restrict__ b1p,
                const float* __restrict__ W2p, const float* __restrict__ b2p,
                const float* __restrict__ Wout, const float* __restrict__ bout,
                float* __restrict__ out)
{
    __shared__ float4 pm [2][50][8];    // 12.8 KB  col-mean chunk partials
    __shared__ float  m  [2][D];        //  1.6 KB
    __shared__ float4 pg1[2][75][8];    // 19.2 KB  g1 chunk partials
    __shared__ float  g1 [2][OUT1];     //  2.4 KB
    __shared__ float4 pg2[2][100][5];   // 16.0 KB  g2 chunk partials
    __shared__ float  g2s[2][OUT2];     //  3.2 KB
    __shared__ float  sm [2][OUT2];     //  3.2 KB

    const int t = threadIdx.x;

    // --- phase 0: reduce partial[2][1000][200] -> m[2][200] -----------------
    // 800 jobs: (chunk of 125 blocks) x (br) x (col-quad). 1 round.
    if (t < 800) {
        const int chunk = t / 100, r = t % 100, br = r / 50, cq = r % 50;
        const float* base =
            partial + ((size_t)br * S1B + (size_t)chunk * 125) * D + cq * 4;
        float4 a = make_float4(0.f, 0.f, 0.f, 0.f);
        #pragma unroll 5
        for (int i = 0; i < 125; ++i) {
            const float4 v = *reinterpret_cast<const float4*>(base + (size_t)i * D);
            a.x += v.x; a.y += v.y; a.z += v.z; a.w += v.w;
        }
        pm[br][cq][chunk] = a;
    }
    __syncthreads();
    if (t < 2 * D) {
        const int br = t / D, col = t % D, cq = col / 4, comp = col % 4;
        float s = 0.f;
        #pragma unroll
        for (int ch = 0; ch < 8; ++ch)
            s += reinterpret_cast<const float*>(&pm[br][cq][ch])[comp];
        m[br][col] = s * (1.0f / (float)N_ROWS);
    }
    __syncthreads();

    // --- phase 1: g1 = relu(m @ W1 + b1) ------------------------------------
    for (int job = t; job < 1200; job += 1024) {
        const int chunk = job / 150, r = job % 150, br = r / 75, jq = r % 75;
        const float* __restrict__ W1 = br ? W1p : W1u;
        const float* __restrict__ mb = m[br];
        const int c0 = chunk * 25;
        float4 a = make_float4(0.f, 0.f, 0.f, 0.f);
        #pragma unroll 5
        for (int i = 0; i < 25; ++i) {
            const float4 w =
                *reinterpret_cast<const float4*>(W1 + (size_t)(c0 + i) * OUT1 + jq * 4);
            const float mv = mb[c0 + i];
            a.x += mv * w.x; a.y += mv * w.y; a.z += mv * w.z; a.w += mv * w.w;
        }
        pg1[br][jq][chunk] = a;
    }
    __syncthreads();
    if (t < 2 * OUT1) {
        const int br = t / OUT1, j = t % OUT1, jq = j / 4, comp = j % 4;
        float s = (br ? b1p : b1u)[j];
        #pragma unroll
        for (int ch = 0; ch < 8; ++ch)
            s += reinterpret_cast<const float*>(&pg1[br][jq][ch])[comp];
        g1[br][j] = fmaxf(s, 0.f);
    }
    __syncthreads();

    // --- phase 2: g2 = g1 @ W2 + b2 -----------------------------------------
    if (t < 1000) {
        const int chunk = t / 200, r = t % 200, br = r / 100, kq = r % 100;
        const float* __restrict__ W2 = br ? W2p : W2u;
        const float* __restrict__ gb = g1[br];
        const int j0 = chunk * 60;
        float4 a = make_float4(0.f, 0.f, 0.f, 0.f);
        #pragma unroll 6
        for (int i = 0; i < 60; ++i) {
            const float4 w =
                *reinterpret_cast<const float4*>(W2 + (size_t)(j0 + i) * OUT2 + kq * 4);
            const float gv = gb[j0 + i];
            a.x += gv * w.x; a.y += gv * w.y; a.z += gv * w.z; a.w += gv * w.w;
        }
        pg2[br][kq][chunk] = a;
    }
    __syncthreads();
    if (t < 2 * OUT2) {
        const int br = t / OUT2, k = t % OUT2, kq = k / 4, comp = k % 4;
        float s = (br ? b2p : b2u)[k];
        #pragma unroll
        for (int ch = 0; ch < 5; ++ch)
            s += reinterpret_cast<const float*>(&pg2[br][kq][ch])[comp];
        g2s[br][k] = s;
    }
    __syncthreads();

    // --- softmax per branch: wave 0 -> br 0, wave 1 -> br 1 -----------------
    const int wave = t >> 6;
    const int lane = t & 63;
    if (wave < 2) {
        const int br = wave;
        float mx = -INFINITY;
        for (int k = lane; k < OUT2; k += 64) mx = fmaxf(mx, g2s[br][k]);
        #pragma unroll
        for (int off = 32; off > 0; off >>= 1) mx = fmaxf(mx, __shfl_xor(mx, off));
        float sum = 0.f;
        for (int k = lane; k < OUT2; k += 64) {
            const float e = expf(g2s[br][k] - mx);
            sm[br][k] = e;
            sum += e;
        }
        #pragma unroll
        for (int off = 32; off > 0; off >>= 1) sum += __shfl_xor(sum, off);
        const float inv = 1.0f / sum;
        for (int k = lane; k < OUT2; k += 64) sm[br][k] *= inv;
    }
    __syncthreads();

    // --- out = sigmoid((sm_u + sm_p) @ W_out + b_out) -----------------------
    if (wave == 0) {
        float s = 0.f;
        for (int k = lane; k < OUT2; k += 64)
            s += (sm[0][k] + sm[1][k]) * Wout[k];
        #pragma unroll
        for (int off = 32; off > 0; off >>= 1) s += __shfl_xor(s, off);
        if (lane == 0)
            out[0] = 1.0f / (1.0f + expf(-(s + bout[0])));
    }
}

// ---------------------------------------------------------------------------
extern "C" void kernel_launch(void* const* d_in, const int* in_sizes, int n_in,
                              void* d_out, int out_size, void* d_ws, size_t ws_size,
                              hipStream_t stream) {
    const float* userH = (const float*)d_in[0];
    const float* postH = (const float*)d_in[1];
    const float* W1u   = (const float*)d_in[2];
    const float* b1u   = (const float*)d_in[3];
    const float* W2u   = (const float*)d_in[4];
    const float* b2u   = (const float*)d_in[5];
    const float* W1p   = (const float*)d_in[6];
    const float* b1p   = (const float*)d_in[7];
    const float* W2p   = (const float*)d_in[8];
    const float* b2p   = (const float*)d_in[9];
    const float* Wout  = (const float*)d_in[10];
    const float* bout  = (const float*)d_in[11];

    float* partial = (float*)d_ws;   // 2*1000*200*4 = 1,600,000 bytes

    dim3 grid1(S1B, 2);
    colsum_kernel<<<grid1, 256, 0, stream>>>(userH, postH, partial);

    mlp_kernel<<<1, 1024, 0, stream>>>(partial,
                                       W1u, b1u, W2u, b2u,
                                       W1p, b1p, W2p, b2p,
                                       Wout, bout, (float*)d_out);
}

// Round 6
// 364.803 us; speedup vs baseline: 1.0883x; 1.0883x over previous
//
#include <hip/hip_runtime.h>
#include <math.h>

#define N_ROWS 200000
#define D 200
#define OUT1 300
#define OUT2 400
#define S1B 1024          // stage-1 blocks per branch (2048 total -> 8 blocks/CU)

using f32x4 = __attribute__((ext_vector_type(4))) float;

// ---------------------------------------------------------------------------
// Stage 1: column-sum of [N_ROWS, D] f32 (branch = blockIdx.y).
// Round-3 structure (best measured) + NON-TEMPORAL loads: streaming reads
// bypass L2/L3 allocation -> no fill/evict churn behind the harness restore.
// partial layout: [2][S1B][D] floats -- coalesced 800 B store per block.
// ---------------------------------------------------------------------------
__global__ __launch_bounds__(256)
void colsum_kernel(const float* __restrict__ userH,
                   const float* __restrict__ postH,
                   float* __restrict__ partial)
{
    const int br = blockIdx.y;
    const float* __restrict__ H = (br == 0) ? userH : postH;
    const int t  = threadIdx.x;
    const int q  = t % 50;   // float4 index within the row
    const int sr = t / 50;   // sub-row 0..4 (lanes 250..255 idle)

    f32x4 acc = {0.f, 0.f, 0.f, 0.f};
    if (sr < 5) {
        for (int row = blockIdx.x * 5 + sr; row < N_ROWS; row += S1B * 5) {
            const f32x4 v = __builtin_nontemporal_load(
                reinterpret_cast<const f32x4*>(H + (size_t)row * D + q * 4));
            acc += v;
        }
    }

    __shared__ float part[5][D];   // 4 KB
    if (sr < 5) {
        part[sr][q * 4 + 0] = acc[0];
        part[sr][q * 4 + 1] = acc[1];
        part[sr][q * 4 + 2] = acc[2];
        part[sr][q * 4 + 3] = acc[3];
    }
    __syncthreads();

    if (t < D) {
        float s = 0.f;
        #pragma unroll
        for (int r = 0; r < 5; ++r) s += part[r][t];
        partial[((size_t)br * S1B + blockIdx.x) * D + t] = s;
    }
}

// ---------------------------------------------------------------------------
// Stage 2: finish reduction -> means -> MLP -> softmax -> sigmoid scalar.
// One block, 1024 threads; chunked dots, float4 along output dims.
// ---------------------------------------------------------------------------
__global__ __launch_bounds__(1024)
void mlp_kernel(const float* __restrict__ partial,
                const float* __restrict__ W1u, const float* __restrict__ b1u,
                const float* __restrict__ W2u, const float* __restrict__ b2u,
                const float* __restrict__ W1p, const float* __restrict__ b1p,
                const float* __restrict__ W2p, const float* __restrict__ b2p,
                const float* __restrict__ Wout, const float* __restrict__ bout,
                float* __restrict__ out)
{
    __shared__ float4 pm [2][50][8];    // 12.8 KB  col-mean chunk partials
    __shared__ float  m  [2][D];        //  1.6 KB
    __shared__ float4 pg1[2][75][8];    // 19.2 KB  g1 chunk partials
    __shared__ float  g1 [2][OUT1];     //  2.4 KB
    __shared__ float4 pg2[2][100][5];   // 16.0 KB  g2 chunk partials
    __shared__ float  g2s[2][OUT2];     //  3.2 KB
    __shared__ float  sm [2][OUT2];     //  3.2 KB

    const int t = threadIdx.x;

    // --- phase 0: reduce partial[2][1024][200] -> m[2][200] -----------------
    if (t < 800) {
        const int chunk = t / 100, r = t % 100, br = r / 50, cq = r % 50;
        const float* base =
            partial + ((size_t)br * S1B + (size_t)chunk * 128) * D + cq * 4;
        float4 a = make_float4(0.f, 0.f, 0.f, 0.f);
        #pragma unroll 8
        for (int i = 0; i < 128; ++i) {
            const float4 v = *reinterpret_cast<const float4*>(base + (size_t)i * D);
            a.x += v.x; a.y += v.y; a.z += v.z; a.w += v.w;
        }
        pm[br][cq][chunk] = a;
    }
    __syncthreads();
    if (t < 2 * D) {
        const int br = t / D, col = t % D, cq = col / 4, comp = col % 4;
        float s = 0.f;
        #pragma unroll
        for (int ch = 0; ch < 8; ++ch)
            s += reinterpret_cast<const float*>(&pm[br][cq][ch])[comp];
        m[br][col] = s * (1.0f / (float)N_ROWS);
    }
    __syncthreads();

    // --- phase 1: g1 = relu(m @ W1 + b1) ------------------------------------
    for (int job = t; job < 1200; job += 1024) {
        const int chunk = job / 150, r = job % 150, br = r / 75, jq = r % 75;
        const float* __restrict__ W1 = br ? W1p : W1u;
        const float* __restrict__ mb = m[br];
        const int c0 = chunk * 25;
        float4 a = make_float4(0.f, 0.f, 0.f, 0.f);
        #pragma unroll 5
        for (int i = 0; i < 25; ++i) {
            const float4 w =
                *reinterpret_cast<const float4*>(W1 + (size_t)(c0 + i) * OUT1 + jq * 4);
            const float mv = mb[c0 + i];
            a.x += mv * w.x; a.y += mv * w.y; a.z += mv * w.z; a.w += mv * w.w;
        }
        pg1[br][jq][chunk] = a;
    }
    __syncthreads();
    if (t < 2 * OUT1) {
        const int br = t / OUT1, j = t % OUT1, jq = j / 4, comp = j % 4;
        float s = (br ? b1p : b1u)[j];
        #pragma unroll
        for (int ch = 0; ch < 8; ++ch)
            s += reinterpret_cast<const float*>(&pg1[br][jq][ch])[comp];
        g1[br][j] = fmaxf(s, 0.f);
    }
    __syncthreads();

    // --- phase 2: g2 = g1 @ W2 + b2 -----------------------------------------
    if (t < 1000) {
        const int chunk = t / 200, r = t % 200, br = r / 100, kq = r % 100;
        const float* __restrict__ W2 = br ? W2p : W2u;
        const float* __restrict__ gb = g1[br];
        const int j0 = chunk * 60;
        float4 a = make_float4(0.f, 0.f, 0.f, 0.f);
        #pragma unroll 6
        for (int i = 0; i < 60; ++i) {
            const float4 w =
                *reinterpret_cast<const float4*>(W2 + (size_t)(j0 + i) * OUT2 + kq * 4);
            const float gv = gb[j0 + i];
            a.x += gv * w.x; a.y += gv * w.y; a.z += gv * w.z; a.w += gv * w.w;
        }
        pg2[br][kq][chunk] = a;
    }
    __syncthreads();
    if (t < 2 * OUT2) {
        const int br = t / OUT2, k = t % OUT2, kq = k / 4, comp = k % 4;
        float s = (br ? b2p : b2u)[k];
        #pragma unroll
        for (int ch = 0; ch < 5; ++ch)
            s += reinterpret_cast<const float*>(&pg2[br][kq][ch])[comp];
        g2s[br][k] = s;
    }
    __syncthreads();

    // --- softmax per branch: wave 0 -> br 0, wave 1 -> br 1 -----------------
    const int wave = t >> 6;
    const int lane = t & 63;
    if (wave < 2) {
        const int br = wave;
        float mx = -INFINITY;
        for (int k = lane; k < OUT2; k += 64) mx = fmaxf(mx, g2s[br][k]);
        #pragma unroll
        for (int off = 32; off > 0; off >>= 1) mx = fmaxf(mx, __shfl_xor(mx, off));
        float sum = 0.f;
        for (int k = lane; k < OUT2; k += 64) {
            const float e = expf(g2s[br][k] - mx);
            sm[br][k] = e;
            sum += e;
        }
        #pragma unroll
        for (int off = 32; off > 0; off >>= 1) sum += __shfl_xor(sum, off);
        const float inv = 1.0f / sum;
        for (int k = lane; k < OUT2; k += 64) sm[br][k] *= inv;
    }
    __syncthreads();

    // --- out = sigmoid((sm_u + sm_p) @ W_out + b_out) -----------------------
    if (wave == 0) {
        float s = 0.f;
        for (int k = lane; k < OUT2; k += 64)
            s += (sm[0][k] + sm[1][k]) * Wout[k];
        #pragma unroll
        for (int off = 32; off > 0; off >>= 1) s += __shfl_xor(s, off);
        if (lane == 0)
            out[0] = 1.0f / (1.0f + expf(-(s + bout[0])));
    }
}

// ---------------------------------------------------------------------------
extern "C" void kernel_launch(void* const* d_in, const int* in_sizes, int n_in,
                              void* d_out, int out_size, void* d_ws, size_t ws_size,
                              hipStream_t stream) {
    const float* userH = (const float*)d_in[0];
    const float* postH = (const float*)d_in[1];
    const float* W1u   = (const float*)d_in[2];
    const float* b1u   = (const float*)d_in[3];
    const float* W2u   = (const float*)d_in[4];
    const float* b2u   = (const float*)d_in[5];
    const float* W1p   = (const float*)d_in[6];
    const float* b1p   = (const float*)d_in[7];
    const float* W2p   = (const float*)d_in[8];
    const float* b2p   = (const float*)d_in[9];
    const float* Wout  = (const float*)d_in[10];
    const float* bout  = (const float*)d_in[11];

    float* partial = (float*)d_ws;   // 2*1024*200*4 = 1,638,400 bytes

    dim3 grid1(S1B, 2);
    colsum_kernel<<<grid1, 256, 0, stream>>>(userH, postH, partial);

    mlp_kernel<<<1, 1024, 0, stream>>>(partial,
                                       W1u, b1u, W2u, b2u,
                                       W1p, b1p, W2p, b2p,
                                       Wout, bout, (float*)d_out);
}

// Round 8
// 336.643 us; speedup vs baseline: 1.1793x; 1.0836x over previous
//
#include <hip/hip_runtime.h>
#include <math.h>

#define N_ROWS 200000
#define D 200
#define OUT1 300
#define OUT2 400
#define S1B 1024          // stage-1 blocks per branch (2048 total -> 8 blocks/CU)

using f32x4 = __attribute__((ext_vector_type(4))) float;

// ---------------------------------------------------------------------------
// Stage 1: column-sum of [N_ROWS, D] f32 (branch = blockIdx.y).
// Round-6 winner: row-pattern + NON-TEMPORAL loads (bypass L2/L3 allocation,
// no fill/evict churn behind the harness restore). UNCHANGED.
// partial layout: [2][S1B][D] floats -- coalesced 800 B store per block.
// ---------------------------------------------------------------------------
__global__ __launch_bounds__(256)
void colsum_kernel(const float* __restrict__ userH,
                   const float* __restrict__ postH,
                   float* __restrict__ partial)
{
    const int br = blockIdx.y;
    const float* __restrict__ H = (br == 0) ? userH : postH;
    const int t  = threadIdx.x;
    const int q  = t % 50;   // float4 index within the row
    const int sr = t / 50;   // sub-row 0..4 (lanes 250..255 idle)

    f32x4 acc = {0.f, 0.f, 0.f, 0.f};
    if (sr < 5) {
        for (int row = blockIdx.x * 5 + sr; row < N_ROWS; row += S1B * 5) {
            const f32x4 v = __builtin_nontemporal_load(
                reinterpret_cast<const f32x4*>(H + (size_t)row * D + q * 4));
            acc += v;
        }
    }

    __shared__ float part[5][D];   // 4 KB
    if (sr < 5) {
        part[sr][q * 4 + 0] = acc[0];
        part[sr][q * 4 + 1] = acc[1];
        part[sr][q * 4 + 2] = acc[2];
        part[sr][q * 4 + 3] = acc[3];
    }
    __syncthreads();

    if (t < D) {
        float s = 0.f;
        #pragma unroll
        for (int r = 0; r < 5; ++r) s += part[r][t];
        partial[((size_t)br * S1B + blockIdx.x) * D + t] = s;
    }
}

// ---------------------------------------------------------------------------
// Stage 2a: partial[2][1024][200] -> partial2[2][8][200]. 16 blocks (8 x 2).
// Block (chunk, br) reduces 128 block-rows; 200 active threads, coalesced
// 800B row segments (sr = row mod 4 interleave).
// ---------------------------------------------------------------------------
__global__ __launch_bounds__(256)
void reduce_kernel(const float* __restrict__ partial,
                   float* __restrict__ partial2)
{
    const int chunk = blockIdx.x;   // 0..7
    const int br    = blockIdx.y;
    const int t     = threadIdx.x;
    const int q  = t % 50;
    const int sr = t / 50;          // 0..3 active (t < 200)

    f32x4 acc = {0.f, 0.f, 0.f, 0.f};
    if (t < 200) {
        const f32x4* __restrict__ P =
            reinterpret_cast<const f32x4*>(partial) + (size_t)br * S1B * 50;
        const int row0 = chunk * 128 + sr;
        #pragma unroll 8
        for (int k = 0; k < 32; ++k)
            acc += P[(size_t)(row0 + 4 * k) * 50 + q];
    }

    __shared__ f32x4 part[4][50];
    if (t < 200) part[sr][q] = acc;
    __syncthreads();

    if (t < 50) {
        const f32x4 s = part[0][t] + part[1][t] + part[2][t] + part[3][t];
        reinterpret_cast<f32x4*>(partial2)[((size_t)br * 8 + chunk) * 50 + t] = s;
    }
}

// ---------------------------------------------------------------------------
// Stage 2b: g1 = relu(m @ W1 + b1). 12 blocks (6 x 2); block owns 50 outputs.
// m recomputed per block from partial2 (1600 tiny loads). Dot-200 split into
// 4 segments of 50 across threads.
// ---------------------------------------------------------------------------
__global__ __launch_bounds__(256)
void g1_kernel(const float* __restrict__ partial2,
               const float* __restrict__ W1u, const float* __restrict__ b1u,
               const float* __restrict__ W1p, const float* __restrict__ b1p,
               float* __restrict__ g1)
{
    const int jb = blockIdx.x;      // 0..5 -> outputs jb*50 .. jb*50+49
    const int br = blockIdx.y;
    const float* __restrict__ W1 = br ? W1p : W1u;
    const float* __restrict__ b1 = br ? b1p : b1u;
    const int t = threadIdx.x;

    __shared__ float m[D];
    if (t < D) {
        float s = 0.f;
        #pragma unroll
        for (int ch = 0; ch < 8; ++ch)
            s += partial2[((size_t)br * 8 + ch) * D + t];
        m[t] = s * (1.0f / (float)N_ROWS);
    }
    __syncthreads();

    const int j   = t % 50;
    const int seg = t / 50;         // 0..3 active (t < 200)
    float p = 0.f;
    if (t < 200) {
        const int c0 = seg * 50;
        for (int c = c0; c < c0 + 50; ++c)
            p += m[c] * W1[(size_t)c * OUT1 + jb * 50 + j];
    }
    __shared__ float pj[4][50];
    if (t < 200) pj[seg][j] = p;
    __syncthreads();

    if (t < 50) {
        const float s = b1[jb * 50 + t] + pj[0][t] + pj[1][t] + pj[2][t] + pj[3][t];
        g1[(size_t)br * OUT1 + jb * 50 + t] = fmaxf(s, 0.f);
    }
}

// ---------------------------------------------------------------------------
// Stage 2c: g2 = g1 @ W2 + b2. 16 blocks (8 x 2); block owns 50 outputs.
// Dot-300 split into 4 segments of 75 across threads.
// ---------------------------------------------------------------------------
__global__ __launch_bounds__(256)
void g2_kernel(const float* __restrict__ g1,
               const float* __restrict__ W2u, const float* __restrict__ b2u,
               const float* __restrict__ W2p, const float* __restrict__ b2p,
               float* __restrict__ g2)
{
    const int kb = blockIdx.x;      // 0..7 -> outputs kb*50 .. kb*50+49
    const int br = blockIdx.y;
    const float* __restrict__ W2 = br ? W2p : W2u;
    const float* __restrict__ b2 = br ? b2p : b2u;
    const int t = threadIdx.x;

    __shared__ float g[OUT1];
    for (int i = t; i < OUT1; i += 256) g[i] = g1[(size_t)br * OUT1 + i];
    __syncthreads();

    const int k   = t % 50;
    const int seg = t / 50;         // 0..3 active (t < 200)
    float p = 0.f;
    if (t < 200) {
        const int j0 = seg * 75;
        for (int j = j0; j < j0 + 75; ++j)
            p += g[j] * W2[(size_t)j * OUT2 + kb * 50 + k];
    }
    __shared__ float pk[4][50];
    if (t < 200) pk[seg][k] = p;
    __syncthreads();

    if (t < 50) {
        g2[(size_t)br * OUT2 + kb * 50 + t] =
            b2[kb * 50 + t] + pk[0][t] + pk[1][t] + pk[2][t] + pk[3][t];
    }
}

// ---------------------------------------------------------------------------
// Stage 2d: softmax per branch -> combine -> dot W_out -> sigmoid. 1 block,
// 128 threads: wave 0 -> branch 0, wave 1 -> branch 1.
// ---------------------------------------------------------------------------
__global__ __launch_bounds__(128)
void finish_kernel(const float* __restrict__ g2,
                   const float* __restrict__ Wout, const float* __restrict__ bout,
                   float* __restrict__ out)
{
    __shared__ float sm[2][OUT2];
    const int wave = threadIdx.x >> 6;
    const int lane = threadIdx.x & 63;
    const int br   = wave;

    float mx = -INFINITY;
    for (int k = lane; k < OUT2; k += 64)
        mx = fmaxf(mx, g2[(size_t)br * OUT2 + k]);
    #pragma unroll
    for (int off = 32; off > 0; off >>= 1) mx = fmaxf(mx, __shfl_xor(mx, off));

    float sum = 0.f;
    for (int k = lane; k < OUT2; k += 64) {
        const float e = expf(g2[(size_t)br * OUT2 + k] - mx);
        sm[br][k] = e;
        sum += e;
    }
    #pragma unroll
    for (int off = 32; off > 0; off >>= 1) sum += __shfl_xor(sum, off);
    const float inv = 1.0f / sum;
    for (int k = lane; k < OUT2; k += 64) sm[br][k] *= inv;
    __syncthreads();

    if (wave == 0) {
        float s = 0.f;
        for (int k = lane; k < OUT2; k += 64)
            s += (sm[0][k] + sm[1][k]) * Wout[k];
        #pragma unroll
        for (int off = 32; off > 0; off >>= 1) s += __shfl_xor(s, off);
        if (lane == 0)
            out[0] = 1.0f / (1.0f + expf(-(s + bout[0])));
    }
}

// ---------------------------------------------------------------------------
extern "C" void kernel_launch(void* const* d_in, const int* in_sizes, int n_in,
                              void* d_out, int out_size, void* d_ws, size_t ws_size,
                              hipStream_t stream) {
    const float* userH = (const float*)d_in[0];
    const float* postH = (const float*)d_in[1];
    const float* W1u   = (const float*)d_in[2];
    const float* b1u   = (const float*)d_in[3];
    const float* W2u   = (const float*)d_in[4];
    const float* b2u   = (const float*)d_in[5];
    const float* W1p   = (const float*)d_in[6];
    const float* b1p   = (const float*)d_in[7];
    const float* W2p   = (const float*)d_in[8];
    const float* b2p   = (const float*)d_in[9];
    const float* Wout  = (const float*)d_in[10];
    const float* bout  = (const float*)d_in[11];

    float* ws       = (float*)d_ws;
    float* partial  = ws;              // 2*1024*200      = 409,600 f (16B-aligned)
    float* partial2 = ws + 409600;     // 2*8*200         =   3,200 f (16B-aligned)
    float* g1       = ws + 412800;     // 2*300           =     600 f
    float* g2       = ws + 413400;     // 2*400           =     800 f

    colsum_kernel<<<dim3(S1B, 2), 256, 0, stream>>>(userH, postH, partial);
    reduce_kernel<<<dim3(8, 2),   256, 0, stream>>>(partial, partial2);
    g1_kernel    <<<dim3(6, 2),   256, 0, stream>>>(partial2, W1u, b1u, W1p, b1p, g1);
    g2_kernel    <<<dim3(8, 2),   256, 0, stream>>>(g1, W2u, b2u, W2p, b2p, g2);
    finish_kernel<<<1,            128, 0, stream>>>(g2, Wout, bout, (float*)d_out);
}